// Round 10
// baseline (684.121 us; speedup 1.0000x reference)
//
#include <hip/hip_runtime.h>
#include <hip/hip_bf16.h>

// GVPDynamicProjection: N=10000, C=2, SI=128, VI=16, H=4, R=32, SH=32, VH=4
// Inputs/outputs: float32. R10 changes vs R9 (275 us; kA 63, kAccum 61):
//  - kA: REVERT to R6-measured 46us shape (256 thr, 16 rows, 31KB LDS,
//    occupancy>LDS-amortization — R7's 32-row version lost 17us to occupancy);
//    stores exp(logit) so kAccum skips expf.
//  - kAccum: atomics + memset again (R6-proven 2.25M atomicAdds cheap), but
//    800 blocks x 256thr = 3200 waves (12.5/CU vs R9's 1.56/SIMD latency trap).
//  - kAttn: same-parity row PAIR per thread (KH/EK/VS/VV LDS reads amortized
//    2x), float4 KH; launch_bounds(256,1). LDS cyc/block 69k->26k.

#define N_  10000
#define C_  2
#define SI_ 128
#define VI_ 16
#define H_  4
#define R_  32
#define SH_ 32
#define VH_ 4
#define NC_ (N_*C_)

typedef const float* __restrict__ fptr;

__device__ __forceinline__ float sigm(float x){ return 1.f/(1.f+__expf(-x)); }

// ---------------- ws layout (float offsets) ----------------
// pexp : [C_*32][N_]   exp(logits), TRANSPOSED      640000
// eqh  : [NC_][100]    per-row eq[4] @0, qh[96] @8  2000000
// sg   : [64][180]     sums: d<176 = sum e^l*x, 176 = sum e^l  (memset 0)
// tkh/tek/tvs/tvv: attn tables
#define OFF_LG   0
#define OFF_EQH  640000
#define OFF_SG   2640000
#define OFF_TKH  2651520
#define OFF_TEK  2657664
#define OFF_TVS  2657920
#define OFF_TVV  2666112
// end 2669184 floats = 10.68 MB

#define SGSTRIDE_ 180

// ================= kernel A: per-row logits + q-path (R6 shape) =============
// 256 threads, 16 rows/block; grid = NC_/16 = 1250
__global__ __launch_bounds__(256) void kA(
    fptr s, fptr v,
    fptr wp_wh, fptr wp_ws_w, fptr wp_ws_b,
    fptr q_wh, fptr q_ws_w, fptr q_ws_b, fptr q_wv, fptr q_wsv_w, fptr q_wsv_b,
    fptr attn_wh, fptr attn_ws_w,
    float* __restrict__ pexp, float* __restrict__ eqh)
{
  // ARENA: phase 0-2 = XT transposed [j][row], stride 20 (16B-aligned float4)
  //        j: 0..127 = s, 128..143 = vn_q, 144..159 = vn_p
  //        phase 2c+ = SIG [16][128], aliases dead XT
  __shared__ __align__(16) float ARENA[160*20];
  __shared__ __align__(16) float VVs[16*48];
  __shared__ __align__(16) float VHQ[16*48];
  __shared__ __align__(16) float SO[16*128];
  __shared__ __align__(16) float GATE[16*16];
  __shared__ __align__(16) float QV[16*48];
  float* const XT  = ARENA;
  float* const SIG = ARENA;

  const int tid  = threadIdx.x;
  const int row0 = blockIdx.x * 16;

  for (int idx = tid; idx < 16*128; idx += 256){
    int r = idx >> 7, j = idx & 127;
    XT[j*20 + r] = s[(row0+r)*128 + j];
  }
  for (int idx = tid; idx < 16*48; idx += 256){
    int r = idx / 48, k = idx - r*48;
    VVs[r*48 + k] = v[(row0+r)*48 + k];
  }
  __syncthreads();

  for (int t = tid; t < 512; t += 256){
    int r = t >> 5, ii = t & 31, path = ii >> 4, i = ii & 15;
    fptr wh = path ? wp_wh : q_wh;
    float h0=0.f, h1=0.f, h2=0.f;
    #pragma unroll
    for (int j = 0; j < 16; j++){
      float w = wh[j*16 + i];
      h0 = fmaf(VVs[r*48 + j*3 + 0], w, h0);
      h1 = fmaf(VVs[r*48 + j*3 + 1], w, h1);
      h2 = fmaf(VVs[r*48 + j*3 + 2], w, h2);
    }
    float vn = sqrtf(fmaxf(h0*h0 + h1*h1 + h2*h2, 1e-8f));
    if (!path){
      VHQ[r*48 +  0 + i] = h0;
      VHQ[r*48 + 16 + i] = h1;
      VHQ[r*48 + 32 + i] = h2;
      XT[(128+i)*20 + r] = vn;
    } else {
      XT[(144+i)*20 + r] = vn;
    }
  }
  __syncthreads();

  // phase 2a: so = [s, vn_q] @ q_ws_w + b (16 rows x 128 cols); acc stays live
  const int colA = tid & 127, rgA = tid >> 7;
  float acc[8];
  {
    float bqs = q_ws_b[colA];
    #pragma unroll
    for (int k = 0; k < 8; k++) acc[k] = bqs;
    #pragma unroll 4
    for (int j = 0; j < 144; j++){
      float w = q_ws_w[j*128 + colA];
      const float* xp = &XT[j*20 + rgA*8];
      float4 x0 = *(const float4*)xp;
      float4 x1 = *(const float4*)(xp + 4);
      acc[0] = fmaf(x0.x, w, acc[0]); acc[1] = fmaf(x0.y, w, acc[1]);
      acc[2] = fmaf(x0.z, w, acc[2]); acc[3] = fmaf(x0.w, w, acc[3]);
      acc[4] = fmaf(x1.x, w, acc[4]); acc[5] = fmaf(x1.y, w, acc[5]);
      acc[6] = fmaf(x1.z, w, acc[6]); acc[7] = fmaf(x1.w, w, acc[7]);
    }
  }
  // phase 2b: logits -> store EXP(logit), TRANSPOSED pexp[(c*32+a)][n]
  {
    const int col = tid & 31, rg = tid >> 5;   // 8 groups x 2 rows (c=0,1)
    float bp = wp_ws_b[col];
    float a0 = bp, a1 = bp;
    #pragma unroll 4
    for (int j = 0; j < 144; j++){
      int jj = (j < 128) ? j : (j + 16);
      float w = wp_ws_w[j*32 + col];
      const float* xp = &XT[jj*20 + rg*2];
      a0 = fmaf(xp[0], w, a0);
      a1 = fmaf(xp[1], w, a1);
    }
    const int n = (row0 >> 1) + rg;
    pexp[(     col)*N_ + n] = __expf(a0);   // no max-sub: |l|<~8, f32-safe
    pexp[(32 + col)*N_ + n] = __expf(a1);
  }
  __syncthreads();                           // XT dead; SIG live

  #pragma unroll
  for (int k = 0; k < 8; k++){
    float so = acc[k];
    float sg_ = sigm(so);
    SIG[(rgA*8 + k)*128 + colA] = sg_;
    SO [(rgA*8 + k)*128 + colA] = so * sg_;  // silu
  }
  __syncthreads();

  {
    const int r = tid >> 4, g = tid & 15;
    float ga = q_wsv_b[g];
    #pragma unroll 8
    for (int o = 0; o < 128; o += 4){
      float4 s4 = *(const float4*)&SIG[r*128 + o];
      ga = fmaf(s4.x, q_wsv_w[(o+0)*16 + g], ga);
      ga = fmaf(s4.y, q_wsv_w[(o+1)*16 + g], ga);
      ga = fmaf(s4.z, q_wsv_w[(o+2)*16 + g], ga);
      ga = fmaf(s4.w, q_wsv_w[(o+3)*16 + g], ga);
    }
    GATE[r*16 + g] = sigm(ga);
  }
  if (tid < 64){
    const int r = tid >> 2, h = tid & 3;
    float e = 0.f;
    #pragma unroll
    for (int t = 0; t < 32; t++)
      e = fmaf(SO[r*128 + h*32 + t], attn_ws_w[t], e);
    eqh[(row0 + r)*100 + h] = e;
  }
  __syncthreads();

  for (int t = tid; t < 16*48; t += 256){
    int r = t / 48, k = t - r*48, i = k / 3, d = k - i*3;
    float a = 0.f;
    #pragma unroll
    for (int j = 0; j < 16; j++)
      a = fmaf(VHQ[r*48 + d*16 + j], q_wv[j*16 + i], a);
    QV[r*48 + k] = a * GATE[r*16 + i];
  }
  __syncthreads();

  for (int t = tid; t < 16*96; t += 256){
    int r = t / 96, k = t - r*96;
    int h = k / 24, rem = k - h*24, d = rem >> 3, ee = rem & 7;
    float a = 0.f;
    #pragma unroll
    for (int i = 0; i < 4; i++)
      a = fmaf(QV[r*48 + (h*4 + i)*3 + d], attn_wh[i*8 + ee], a);
    eqh[(row0 + r)*100 + 8 + k] = a;
  }
}

// ===== kAccum: weighted sums via atomics, 800 blocks = 3200 waves ==========
// grid: c(2) x ah(2) x chunk(200 of 50 n); 256 thr = ag(4) x dl(64)
__global__ __launch_bounds__(256) void kAccum(const float* __restrict__ pexp,
                                              fptr s, fptr v,
                                              float* __restrict__ sg)
{
  const int b = blockIdx.x;
  const int c = b & 1, ah = (b >> 1) & 1, chunk = b >> 2;
  const int n0 = chunk * 50;
  const int tid = threadIdx.x;
  const int ag = tid >> 6, dl = tid & 63;
  const int abase = ah*16 + ag*4;

  const float* pb = pexp + (c*32 + abase)*N_;
  float acc[4][3] = {};
  float dn[4] = {};

  #pragma unroll 2
  for (int n = n0; n < n0 + 50; n++){
    const int rc = n*2 + c;
    float pw[4];
    #pragma unroll
    for (int aa = 0; aa < 4; aa++){
      pw[aa] = pb[aa*N_ + n];
      dn[aa] += pw[aa];
    }
    #pragma unroll
    for (int dd = 0; dd < 3; dd++){
      int d = dl + 64*dd;
      if (d < 176){
        float xv = (d < 128) ? s[rc*128 + d] : v[rc*48 + d - 128];
        #pragma unroll
        for (int aa = 0; aa < 4; aa++)
          acc[aa][dd] = fmaf(pw[aa], xv, acc[aa][dd]);
      }
    }
  }
  #pragma unroll
  for (int aa = 0; aa < 4; aa++){
    const int base = (c*32 + abase + aa)*SGSTRIDE_;
    #pragma unroll
    for (int dd = 0; dd < 3; dd++){
      int d = dl + 64*dd;
      if (d < 176) atomicAdd(&sg[base + d], acc[aa][dd]);
    }
    if (dl == 0) atomicAdd(&sg[base + 176], dn[aa]);
  }
}

// ================= kSmall: normalize + k/vv GVP + attn tables ===============
// grid: 64 blocks = (a=r, c)
__global__ __launch_bounds__(256) void kSmall(
    const float* __restrict__ sg,
    fptr k_wh, fptr k_ws_w, fptr k_ws_b, fptr k_wv, fptr k_wsv_w, fptr k_wsv_b,
    fptr vv_wh, fptr vv_ws_w, fptr vv_ws_b, fptr vv_wv, fptr vv_wsv_w, fptr vv_wsv_b,
    fptr attn_wh, fptr attn_ws_w,
    float* __restrict__ tkh, float* __restrict__ tek,
    float* __restrict__ tvs, float* __restrict__ tvv)
{
  const int b = blockIdx.x, r = b >> 1, c = b & 1;
  const int tid = threadIdx.x;
  __shared__ float X[176];
  __shared__ float VN[2][16];
  __shared__ float VH[2][48];
  __shared__ float SOk[128], SOv[128];
  __shared__ float G[2][16];
  __shared__ float KV[48];

  if (tid < 176){
    const float* p = sg + (c*32 + r)*SGSTRIDE_;
    X[tid] = p[tid] / p[176];          // normalize by sum e^l (broadcast load)
  }
  __syncthreads();

  if (tid < 32){
    int path = tid >> 4, i = tid & 15;
    fptr wh = path ? vv_wh : k_wh;
    float h0=0.f, h1=0.f, h2=0.f;
    #pragma unroll
    for (int j = 0; j < 16; j++){
      float w = wh[j*16 + i];
      h0 = fmaf(X[128 + j*3 + 0], w, h0);
      h1 = fmaf(X[128 + j*3 + 1], w, h1);
      h2 = fmaf(X[128 + j*3 + 2], w, h2);
    }
    VH[path][ 0 + i] = h0; VH[path][16 + i] = h1; VH[path][32 + i] = h2;
    VN[path][i] = sqrtf(fmaxf(h0*h0 + h1*h1 + h2*h2, 1e-8f));
  }
  __syncthreads();

  {
    int path = tid >> 7, col = tid & 127;
    fptr W  = path ? vv_ws_w : k_ws_w;
    fptr Bb = path ? vv_ws_b : k_ws_b;
    float so = Bb[col];
    for (int j = 0; j < 128; j++) so = fmaf(X[j], W[j*128 + col], so);
    #pragma unroll
    for (int i = 0; i < 16; i++)  so = fmaf(VN[path][i], W[(128+i)*128 + col], so);
    (path ? SOv : SOk)[col] = so;
  }
  __syncthreads();

  if (tid < 32){
    int path = tid >> 4, g = tid & 15;
    fptr Wsv = path ? vv_wsv_w : k_wsv_w;
    fptr Bsv = path ? vv_wsv_b : k_wsv_b;
    const float* SOp = path ? SOv : SOk;
    float ga = Bsv[g];
    for (int o = 0; o < 128; o++)
      ga = fmaf(sigm(SOp[o]), Wsv[o*16 + g], ga);
    G[path][g] = sigm(ga);
  } else if (tid < 36){
    int h = tid - 32;
    float e = 0.f;
    #pragma unroll
    for (int t = 0; t < 32; t++){
      float so = SOk[h*32 + t];
      e = fmaf(so * sigm(so), attn_ws_w[32 + t], e);
    }
    tek[(r*2 + c)*4 + h] = e;
  } else if (tid >= 64 && tid < 192){
    int o = tid - 64;
    float so = SOv[o];
    tvs[(r*2 + c)*128 + o] = so * sigm(so);
  }
  __syncthreads();

  if (tid < 96){
    int path = tid / 48, k = tid % 48, i = k / 3, d = k - i*3;
    fptr Wv = path ? vv_wv : k_wv;
    float vo = 0.f;
    #pragma unroll
    for (int j = 0; j < 16; j++)
      vo = fmaf(VH[path][d*16 + j], Wv[j*16 + i], vo);
    float gv = vo * G[path][i];
    if (path == 0) KV[k] = gv;
    else {
      int h = i >> 2, ii = i & 3;
      tvv[(((r*2 + c)*4 + h)*4 + ii)*3 + d] = gv;
    }
  }
  __syncthreads();

  if (tid < 96){
    int h = tid / 24, rem = tid % 24, d = rem >> 3, ee = rem & 7;
    float a = 0.f;
    #pragma unroll
    for (int i = 0; i < 4; i++)
      a = fmaf(KV[(h*4 + i)*3 + d], attn_wh[(4 + i)*8 + ee], a);
    tkh[((r*2 + c)*4 + h)*24 + d*8 + ee] = a;
  }
}

// ================= kAttn: attention + outputs ==============================
// 256 threads = 64 same-parity row-PAIRS x 4 heads; 128 rows/block.
// KH/EK/VS/VV LDS reads shared across the pair; float4 everywhere.
__global__ __launch_bounds__(256, 1) void kAttn(
    const float* __restrict__ eqh,
    const float* __restrict__ tkh, const float* __restrict__ tek,
    const float* __restrict__ tvs, const float* __restrict__ tvv,
    fptr attn_ws_w, fptr attn_ws_b,
    float* __restrict__ out)
{
  __shared__ __align__(16) float KH[6144];
  __shared__ __align__(16) float EK[256];
  __shared__ __align__(16) float VS[256*36];   // rows padded 32->36
  __shared__ __align__(16) float VVt[3072];
  const int tid = threadIdx.x;

  for (int i = tid; i < 6144; i += 256) KH[i] = tkh[i];
  if (tid < 256) EK[tid] = tek[tid];
  for (int i = tid; i < 8192; i += 256){ int base = i >> 5, t = i & 31; VS[base*36 + t] = tvs[i]; }
  for (int i = tid; i < 3072; i += 256) VVt[i] = tvv[i];

  float wsn[8];
  #pragma unroll
  for (int ee = 0; ee < 8; ee++) wsn[ee] = attn_ws_w[64 + ee];
  const float wb = attn_ws_b[0];
  __syncthreads();

  const int p = tid >> 2, h = tid & 3;
  const int q = ((p >> 1) << 2) + (p & 1);     // pairs (q, q+2), same parity
  const int rowA = blockIdx.x*128 + q;
  const int rowB = rowA + 2;
  const int c = q & 1;
  const bool okA = rowA < NC_, okB = rowB < NC_;

  float qa[24], qb[24];
  float eqA = 0.f, eqB = 0.f;
  #pragma unroll
  for (int k = 0; k < 24; k++){ qa[k] = 0.f; qb[k] = 0.f; }
  if (okA){
    eqA = eqh[rowA*100 + h];
    const float4* qp = (const float4*)&eqh[rowA*100 + 8 + h*24];
    #pragma unroll
    for (int k = 0; k < 6; k++){
      float4 t4 = qp[k];
      qa[k*4+0]=t4.x; qa[k*4+1]=t4.y; qa[k*4+2]=t4.z; qa[k*4+3]=t4.w;
    }
  }
  if (okB){
    eqB = eqh[rowB*100 + h];
    const float4* qp = (const float4*)&eqh[rowB*100 + 8 + h*24];
    #pragma unroll
    for (int k = 0; k < 6; k++){
      float4 t4 = qp[k];
      qb[k*4+0]=t4.x; qb[k*4+1]=t4.y; qb[k*4+2]=t4.z; qb[k*4+3]=t4.w;
    }
  }

  float sa[32], sb[32], va[12], vb[12];
  #pragma unroll
  for (int k = 0; k < 32; k++){ sa[k]=0.f; sb[k]=0.f; }
  #pragma unroll
  for (int k = 0; k < 12; k++){ va[k]=0.f; vb[k]=0.f; }
  float denA = 0.f, denB = 0.f;

  #pragma unroll
  for (int r = 0; r < 32; r++){
    const int base = (r*2 + c)*4 + h;
    float kh[24];
    {
      const float4* kp4 = (const float4*)&KH[base*24];
      #pragma unroll
      for (int qq = 0; qq < 6; qq++){
        float4 t4 = kp4[qq];
        kh[qq*4+0]=t4.x; kh[qq*4+1]=t4.y; kh[qq*4+2]=t4.z; kh[qq*4+3]=t4.w;
      }
    }
    float enA = 0.f, enB = 0.f;
    #pragma unroll
    for (int ee = 0; ee < 8; ee++){
      float a0 = qa[ee] + kh[ee], a1 = qa[8+ee] + kh[8+ee], a2 = qa[16+ee] + kh[16+ee];
      enA = fmaf(sqrtf(fmaxf(a0*a0 + a1*a1 + a2*a2, 1e-8f)), wsn[ee], enA);
      float b0 = qb[ee] + kh[ee], b1 = qb[8+ee] + kh[8+ee], b2 = qb[16+ee] + kh[16+ee];
      enB = fmaf(sqrtf(fmaxf(b0*b0 + b1*b1 + b2*b2, 1e-8f)), wsn[ee], enB);
    }
    const float ekv = EK[base];
    // no max-sub: |ev| small (0.177-scaled O(1) logits), f32-safe
    const float wA = okA ? __expf((eqA + ekv + enA + wb) * 0.17677669529663687f) : 0.f;
    const float wB = okB ? __expf((eqB + ekv + enB + wb) * 0.17677669529663687f) : 0.f;
    denA += wA; denB += wB;

    const float4* vp4 = (const float4*)&VS[base*36];
    #pragma unroll
    for (int qq = 0; qq < 8; qq++){
      float4 t4 = vp4[qq];
      sa[qq*4+0] = fmaf(wA, t4.x, sa[qq*4+0]); sb[qq*4+0] = fmaf(wB, t4.x, sb[qq*4+0]);
      sa[qq*4+1] = fmaf(wA, t4.y, sa[qq*4+1]); sb[qq*4+1] = fmaf(wB, t4.y, sb[qq*4+1]);
      sa[qq*4+2] = fmaf(wA, t4.z, sa[qq*4+2]); sb[qq*4+2] = fmaf(wB, t4.z, sb[qq*4+2]);
      sa[qq*4+3] = fmaf(wA, t4.w, sa[qq*4+3]); sb[qq*4+3] = fmaf(wB, t4.w, sb[qq*4+3]);
    }
    const float4* vv4 = (const float4*)&VVt[base*12];
    #pragma unroll
    for (int qq = 0; qq < 3; qq++){
      float4 t4 = vv4[qq];
      va[qq*4+0] = fmaf(wA, t4.x, va[qq*4+0]); vb[qq*4+0] = fmaf(wB, t4.x, vb[qq*4+0]);
      va[qq*4+1] = fmaf(wA, t4.y, va[qq*4+1]); vb[qq*4+1] = fmaf(wB, t4.y, vb[qq*4+1]);
      va[qq*4+2] = fmaf(wA, t4.z, va[qq*4+2]); vb[qq*4+2] = fmaf(wB, t4.z, vb[qq*4+2]);
      va[qq*4+3] = fmaf(wA, t4.w, va[qq*4+3]); vb[qq*4+3] = fmaf(wB, t4.w, vb[qq*4+3]);
    }
  }

  if (okA){
    const float inv = 1.f / denA;
    float4* po = (float4*)&out[rowA*128 + h*32];
    #pragma unroll
    for (int qq = 0; qq < 8; qq++)
      po[qq] = make_float4(sa[qq*4]*inv, sa[qq*4+1]*inv, sa[qq*4+2]*inv, sa[qq*4+3]*inv);
    float4* pv = (float4*)&out[NC_*128 + rowA*48 + h*12];
    #pragma unroll
    for (int qq = 0; qq < 3; qq++)
      pv[qq] = make_float4(va[qq*4]*inv, va[qq*4+1]*inv, va[qq*4+2]*inv, va[qq*4+3]*inv);
  }
  if (okB){
    const float inv = 1.f / denB;
    float4* po = (float4*)&out[rowB*128 + h*32];
    #pragma unroll
    for (int qq = 0; qq < 8; qq++)
      po[qq] = make_float4(sb[qq*4]*inv, sb[qq*4+1]*inv, sb[qq*4+2]*inv, sb[qq*4+3]*inv);
    float4* pv = (float4*)&out[NC_*128 + rowB*48 + h*12];
    #pragma unroll
    for (int qq = 0; qq < 3; qq++)
      pv[qq] = make_float4(vb[qq*4]*inv, vb[qq*4+1]*inv, vb[qq*4+2]*inv, vb[qq*4+3]*inv);
  }
}

extern "C" void kernel_launch(void* const* d_in, const int* in_sizes, int n_in,
                              void* d_out, int out_size, void* d_ws, size_t ws_size,
                              hipStream_t stream)
{
  fptr s        = (fptr)d_in[0];
  fptr v        = (fptr)d_in[1];
  fptr wp_wh    = (fptr)d_in[2];
  fptr wp_ws_w  = (fptr)d_in[3];
  fptr wp_ws_b  = (fptr)d_in[4];
  fptr q_wh     = (fptr)d_in[5];
  fptr q_ws_w   = (fptr)d_in[6];
  fptr q_ws_b   = (fptr)d_in[7];
  fptr q_wv     = (fptr)d_in[8];
  fptr q_wsv_w  = (fptr)d_in[9];
  fptr q_wsv_b  = (fptr)d_in[10];
  fptr k_wh     = (fptr)d_in[11];
  fptr k_ws_w   = (fptr)d_in[12];
  fptr k_ws_b   = (fptr)d_in[13];
  fptr k_wv     = (fptr)d_in[14];
  fptr k_wsv_w  = (fptr)d_in[15];
  fptr k_wsv_b  = (fptr)d_in[16];
  fptr vv_wh    = (fptr)d_in[17];
  fptr vv_ws_w  = (fptr)d_in[18];
  fptr vv_ws_b  = (fptr)d_in[19];
  fptr vv_wv    = (fptr)d_in[20];
  fptr vv_wsv_w = (fptr)d_in[21];
  fptr vv_wsv_b = (fptr)d_in[22];
  fptr attn_wh  = (fptr)d_in[23];
  fptr attn_ws_w= (fptr)d_in[24];
  fptr attn_ws_b= (fptr)d_in[25];

  float* ws   = (float*)d_ws;
  float* pexp = ws + OFF_LG;
  float* eqh  = ws + OFF_EQH;
  float* sg   = ws + OFF_SG;
  float* tkh  = ws + OFF_TKH;
  float* tek  = ws + OFF_TEK;
  float* tvs  = ws + OFF_TVS;
  float* tvv  = ws + OFF_TVV;

  hipMemsetAsync(sg, 0, 64*SGSTRIDE_*sizeof(float), stream);

  kA<<<NC_/16, 256, 0, stream>>>(s, v, wp_wh, wp_ws_w, wp_ws_b,
                                 q_wh, q_ws_w, q_ws_b, q_wv, q_wsv_w, q_wsv_b,
                                 attn_wh, attn_ws_w, pexp, eqh);
  kAccum<<<800, 256, 0, stream>>>(pexp, s, v, sg);
  kSmall<<<64, 256, 0, stream>>>(sg,
                                 k_wh, k_ws_w, k_ws_b, k_wv, k_wsv_w, k_wsv_b,
                                 vv_wh, vv_ws_w, vv_ws_b, vv_wv, vv_wsv_w, vv_wsv_b,
                                 attn_wh, attn_ws_w, tkh, tek, tvs, tvv);
  kAttn<<<(NC_ + 127)/128, 256, 0, stream>>>(eqh, tkh, tek, tvs, tvv,
                                             attn_ws_w, attn_ws_b, (float*)d_out);
}

// Round 11
// 244.811 us; speedup vs baseline: 2.7945x; 2.7945x over previous
//
#include <hip/hip_runtime.h>
#include <hip/hip_bf16.h>

// GVPDynamicProjection: N=10000, C=2, SI=128, VI=16, H=4, R=32, SH=32, VH=4
// Inputs/outputs: float32. R11 vs R10 (684 us): kAttn row-pair variant spilled
// (VGPR=256, 640 MB scratch traffic, 477 us). REVERT kAttn to the R9-measured
// single-row version (sub-61us). CONSTRAINT (measured twice, R8+R10): kAttn
// must stay <= ~100 live floats/thread; LDS-read amortization via more
// per-thread state always loses here.
// kA (R6 shape + pexp), kAccum (800-blk atomics), kSmall unchanged from R10.

#define N_  10000
#define C_  2
#define SI_ 128
#define VI_ 16
#define H_  4
#define R_  32
#define SH_ 32
#define VH_ 4
#define NC_ (N_*C_)

typedef const float* __restrict__ fptr;

__device__ __forceinline__ float sigm(float x){ return 1.f/(1.f+__expf(-x)); }

// ---------------- ws layout (float offsets) ----------------
// pexp : [C_*32][N_]   exp(logits), TRANSPOSED      640000
// eqh  : [NC_][100]    per-row eq[4] @0, qh[96] @8  2000000
// sg   : [64][180]     sums: d<176 = sum e^l*x, 176 = sum e^l  (memset 0)
// tkh/tek/tvs/tvv: attn tables
#define OFF_LG   0
#define OFF_EQH  640000
#define OFF_SG   2640000
#define OFF_TKH  2651520
#define OFF_TEK  2657664
#define OFF_TVS  2657920
#define OFF_TVV  2666112

#define SGSTRIDE_ 180

// ================= kernel A: per-row logits + q-path (R6 shape) =============
// 256 threads, 16 rows/block; grid = NC_/16 = 1250
__global__ __launch_bounds__(256) void kA(
    fptr s, fptr v,
    fptr wp_wh, fptr wp_ws_w, fptr wp_ws_b,
    fptr q_wh, fptr q_ws_w, fptr q_ws_b, fptr q_wv, fptr q_wsv_w, fptr q_wsv_b,
    fptr attn_wh, fptr attn_ws_w,
    float* __restrict__ pexp, float* __restrict__ eqh)
{
  __shared__ __align__(16) float ARENA[160*20];
  __shared__ __align__(16) float VVs[16*48];
  __shared__ __align__(16) float VHQ[16*48];
  __shared__ __align__(16) float SO[16*128];
  __shared__ __align__(16) float GATE[16*16];
  __shared__ __align__(16) float QV[16*48];
  float* const XT  = ARENA;
  float* const SIG = ARENA;

  const int tid  = threadIdx.x;
  const int row0 = blockIdx.x * 16;

  for (int idx = tid; idx < 16*128; idx += 256){
    int r = idx >> 7, j = idx & 127;
    XT[j*20 + r] = s[(row0+r)*128 + j];
  }
  for (int idx = tid; idx < 16*48; idx += 256){
    int r = idx / 48, k = idx - r*48;
    VVs[r*48 + k] = v[(row0+r)*48 + k];
  }
  __syncthreads();

  for (int t = tid; t < 512; t += 256){
    int r = t >> 5, ii = t & 31, path = ii >> 4, i = ii & 15;
    fptr wh = path ? wp_wh : q_wh;
    float h0=0.f, h1=0.f, h2=0.f;
    #pragma unroll
    for (int j = 0; j < 16; j++){
      float w = wh[j*16 + i];
      h0 = fmaf(VVs[r*48 + j*3 + 0], w, h0);
      h1 = fmaf(VVs[r*48 + j*3 + 1], w, h1);
      h2 = fmaf(VVs[r*48 + j*3 + 2], w, h2);
    }
    float vn = sqrtf(fmaxf(h0*h0 + h1*h1 + h2*h2, 1e-8f));
    if (!path){
      VHQ[r*48 +  0 + i] = h0;
      VHQ[r*48 + 16 + i] = h1;
      VHQ[r*48 + 32 + i] = h2;
      XT[(128+i)*20 + r] = vn;
    } else {
      XT[(144+i)*20 + r] = vn;
    }
  }
  __syncthreads();

  const int colA = tid & 127, rgA = tid >> 7;
  float acc[8];
  {
    float bqs = q_ws_b[colA];
    #pragma unroll
    for (int k = 0; k < 8; k++) acc[k] = bqs;
    #pragma unroll 4
    for (int j = 0; j < 144; j++){
      float w = q_ws_w[j*128 + colA];
      const float* xp = &XT[j*20 + rgA*8];
      float4 x0 = *(const float4*)xp;
      float4 x1 = *(const float4*)(xp + 4);
      acc[0] = fmaf(x0.x, w, acc[0]); acc[1] = fmaf(x0.y, w, acc[1]);
      acc[2] = fmaf(x0.z, w, acc[2]); acc[3] = fmaf(x0.w, w, acc[3]);
      acc[4] = fmaf(x1.x, w, acc[4]); acc[5] = fmaf(x1.y, w, acc[5]);
      acc[6] = fmaf(x1.z, w, acc[6]); acc[7] = fmaf(x1.w, w, acc[7]);
    }
  }
  {
    const int col = tid & 31, rg = tid >> 5;
    float bp = wp_ws_b[col];
    float a0 = bp, a1 = bp;
    #pragma unroll 4
    for (int j = 0; j < 144; j++){
      int jj = (j < 128) ? j : (j + 16);
      float w = wp_ws_w[j*32 + col];
      const float* xp = &XT[jj*20 + rg*2];
      a0 = fmaf(xp[0], w, a0);
      a1 = fmaf(xp[1], w, a1);
    }
    const int n = (row0 >> 1) + rg;
    pexp[(     col)*N_ + n] = __expf(a0);   // no max-sub: |l|<~8, f32-safe
    pexp[(32 + col)*N_ + n] = __expf(a1);
  }
  __syncthreads();

  #pragma unroll
  for (int k = 0; k < 8; k++){
    float so = acc[k];
    float sg_ = sigm(so);
    SIG[(rgA*8 + k)*128 + colA] = sg_;
    SO [(rgA*8 + k)*128 + colA] = so * sg_;
  }
  __syncthreads();

  {
    const int r = tid >> 4, g = tid & 15;
    float ga = q_wsv_b[g];
    #pragma unroll 8
    for (int o = 0; o < 128; o += 4){
      float4 s4 = *(const float4*)&SIG[r*128 + o];
      ga = fmaf(s4.x, q_wsv_w[(o+0)*16 + g], ga);
      ga = fmaf(s4.y, q_wsv_w[(o+1)*16 + g], ga);
      ga = fmaf(s4.z, q_wsv_w[(o+2)*16 + g], ga);
      ga = fmaf(s4.w, q_wsv_w[(o+3)*16 + g], ga);
    }
    GATE[r*16 + g] = sigm(ga);
  }
  if (tid < 64){
    const int r = tid >> 2, h = tid & 3;
    float e = 0.f;
    #pragma unroll
    for (int t = 0; t < 32; t++)
      e = fmaf(SO[r*128 + h*32 + t], attn_ws_w[t], e);
    eqh[(row0 + r)*100 + h] = e;
  }
  __syncthreads();

  for (int t = tid; t < 16*48; t += 256){
    int r = t / 48, k = t - r*48, i = k / 3, d = k - i*3;
    float a = 0.f;
    #pragma unroll
    for (int j = 0; j < 16; j++)
      a = fmaf(VHQ[r*48 + d*16 + j], q_wv[j*16 + i], a);
    QV[r*48 + k] = a * GATE[r*16 + i];
  }
  __syncthreads();

  for (int t = tid; t < 16*96; t += 256){
    int r = t / 96, k = t - r*96;
    int h = k / 24, rem = k - h*24, d = rem >> 3, ee = rem & 7;
    float a = 0.f;
    #pragma unroll
    for (int i = 0; i < 4; i++)
      a = fmaf(QV[r*48 + (h*4 + i)*3 + d], attn_wh[i*8 + ee], a);
    eqh[(row0 + r)*100 + 8 + k] = a;
  }
}

// ===== kAccum: weighted sums via atomics, 800 blocks = 3200 waves ==========
__global__ __launch_bounds__(256) void kAccum(const float* __restrict__ pexp,
                                              fptr s, fptr v,
                                              float* __restrict__ sg)
{
  const int b = blockIdx.x;
  const int c = b & 1, ah = (b >> 1) & 1, chunk = b >> 2;
  const int n0 = chunk * 50;
  const int tid = threadIdx.x;
  const int ag = tid >> 6, dl = tid & 63;
  const int abase = ah*16 + ag*4;

  const float* pb = pexp + (c*32 + abase)*N_;
  float acc[4][3] = {};
  float dn[4] = {};

  #pragma unroll 2
  for (int n = n0; n < n0 + 50; n++){
    const int rc = n*2 + c;
    float pw[4];
    #pragma unroll
    for (int aa = 0; aa < 4; aa++){
      pw[aa] = pb[aa*N_ + n];
      dn[aa] += pw[aa];
    }
    #pragma unroll
    for (int dd = 0; dd < 3; dd++){
      int d = dl + 64*dd;
      if (d < 176){
        float xv = (d < 128) ? s[rc*128 + d] : v[rc*48 + d - 128];
        #pragma unroll
        for (int aa = 0; aa < 4; aa++)
          acc[aa][dd] = fmaf(pw[aa], xv, acc[aa][dd]);
      }
    }
  }
  #pragma unroll
  for (int aa = 0; aa < 4; aa++){
    const int base = (c*32 + abase + aa)*SGSTRIDE_;
    #pragma unroll
    for (int dd = 0; dd < 3; dd++){
      int d = dl + 64*dd;
      if (d < 176) atomicAdd(&sg[base + d], acc[aa][dd]);
    }
    if (dl == 0) atomicAdd(&sg[base + 176], dn[aa]);
  }
}

// ================= kSmall: normalize + k/vv GVP + attn tables ===============
__global__ __launch_bounds__(256) void kSmall(
    const float* __restrict__ sg,
    fptr k_wh, fptr k_ws_w, fptr k_ws_b, fptr k_wv, fptr k_wsv_w, fptr k_wsv_b,
    fptr vv_wh, fptr vv_ws_w, fptr vv_ws_b, fptr vv_wv, fptr vv_wsv_w, fptr vv_wsv_b,
    fptr attn_wh, fptr attn_ws_w,
    float* __restrict__ tkh, float* __restrict__ tek,
    float* __restrict__ tvs, float* __restrict__ tvv)
{
  const int b = blockIdx.x, r = b >> 1, c = b & 1;
  const int tid = threadIdx.x;
  __shared__ float X[176];
  __shared__ float VN[2][16];
  __shared__ float VH[2][48];
  __shared__ float SOk[128], SOv[128];
  __shared__ float G[2][16];
  __shared__ float KV[48];

  if (tid < 176){
    const float* p = sg + (c*32 + r)*SGSTRIDE_;
    X[tid] = p[tid] / p[176];
  }
  __syncthreads();

  if (tid < 32){
    int path = tid >> 4, i = tid & 15;
    fptr wh = path ? vv_wh : k_wh;
    float h0=0.f, h1=0.f, h2=0.f;
    #pragma unroll
    for (int j = 0; j < 16; j++){
      float w = wh[j*16 + i];
      h0 = fmaf(X[128 + j*3 + 0], w, h0);
      h1 = fmaf(X[128 + j*3 + 1], w, h1);
      h2 = fmaf(X[128 + j*3 + 2], w, h2);
    }
    VH[path][ 0 + i] = h0; VH[path][16 + i] = h1; VH[path][32 + i] = h2;
    VN[path][i] = sqrtf(fmaxf(h0*h0 + h1*h1 + h2*h2, 1e-8f));
  }
  __syncthreads();

  {
    int path = tid >> 7, col = tid & 127;
    fptr W  = path ? vv_ws_w : k_ws_w;
    fptr Bb = path ? vv_ws_b : k_ws_b;
    float so = Bb[col];
    for (int j = 0; j < 128; j++) so = fmaf(X[j], W[j*128 + col], so);
    #pragma unroll
    for (int i = 0; i < 16; i++)  so = fmaf(VN[path][i], W[(128+i)*128 + col], so);
    (path ? SOv : SOk)[col] = so;
  }
  __syncthreads();

  if (tid < 32){
    int path = tid >> 4, g = tid & 15;
    fptr Wsv = path ? vv_wsv_w : k_wsv_w;
    fptr Bsv = path ? vv_wsv_b : k_wsv_b;
    const float* SOp = path ? SOv : SOk;
    float ga = Bsv[g];
    for (int o = 0; o < 128; o++)
      ga = fmaf(sigm(SOp[o]), Wsv[o*16 + g], ga);
    G[path][g] = sigm(ga);
  } else if (tid < 36){
    int h = tid - 32;
    float e = 0.f;
    #pragma unroll
    for (int t = 0; t < 32; t++){
      float so = SOk[h*32 + t];
      e = fmaf(so * sigm(so), attn_ws_w[32 + t], e);
    }
    tek[(r*2 + c)*4 + h] = e;
  } else if (tid >= 64 && tid < 192){
    int o = tid - 64;
    float so = SOv[o];
    tvs[(r*2 + c)*128 + o] = so * sigm(so);
  }
  __syncthreads();

  if (tid < 96){
    int path = tid / 48, k = tid % 48, i = k / 3, d = k - i*3;
    fptr Wv = path ? vv_wv : k_wv;
    float vo = 0.f;
    #pragma unroll
    for (int j = 0; j < 16; j++)
      vo = fmaf(VH[path][d*16 + j], Wv[j*16 + i], vo);
    float gv = vo * G[path][i];
    if (path == 0) KV[k] = gv;
    else {
      int h = i >> 2, ii = i & 3;
      tvv[(((r*2 + c)*4 + h)*4 + ii)*3 + d] = gv;
    }
  }
  __syncthreads();

  if (tid < 96){
    int h = tid / 24, rem = tid % 24, d = rem >> 3, ee = rem & 7;
    float a = 0.f;
    #pragma unroll
    for (int i = 0; i < 4; i++)
      a = fmaf(KV[(h*4 + i)*3 + d], attn_wh[(4 + i)*8 + ee], a);
    tkh[((r*2 + c)*4 + h)*24 + d*8 + ee] = a;
  }
}

// ================= kAttn (R9-measured): one row/thread ======================
// 512 threads = 128 rows x 4 heads. Single r-loop, no-max softmax, no e[] array.
// Scalar KH reads (broadcast), float4 VS/VV immediate accumulation, float4 stores.
__global__ __launch_bounds__(512, 1) void kAttn(
    const float* __restrict__ eqh,
    const float* __restrict__ tkh, const float* __restrict__ tek,
    const float* __restrict__ tvs, const float* __restrict__ tvv,
    fptr attn_ws_w, fptr attn_ws_b,
    float* __restrict__ out)
{
  __shared__ __align__(16) float KH[6144];
  __shared__ __align__(16) float EK[256];
  __shared__ __align__(16) float VS[256*36];
  __shared__ __align__(16) float VVt[3072];
  const int tid = threadIdx.x;

  for (int i = tid; i < 6144; i += 512) KH[i] = tkh[i];
  if (tid < 256) EK[tid] = tek[tid];
  for (int i = tid; i < 8192; i += 512){ int base = i >> 5, t = i & 31; VS[base*36 + t] = tvs[i]; }
  for (int i = tid; i < 3072; i += 512) VVt[i] = tvv[i];

  float wsn[8];
  #pragma unroll
  for (int ee = 0; ee < 8; ee++) wsn[ee] = attn_ws_w[64 + ee];
  const float wb = attn_ws_b[0];
  __syncthreads();

  const int row = blockIdx.x*128 + (tid >> 2);
  const int h = tid & 3;
  if (row < NC_){
    const int c = row & 1;
    const float eq = eqh[row*100 + h];
    float qh[24];
    {
      const float4* qp = (const float4*)&eqh[row*100 + 8 + h*24];
      #pragma unroll
      for (int k = 0; k < 6; k++){
        float4 t4 = qp[k];
        qh[k*4+0] = t4.x; qh[k*4+1] = t4.y; qh[k*4+2] = t4.z; qh[k*4+3] = t4.w;
      }
    }
    float4 accs4[8];
    float4 accv4[3];
    #pragma unroll
    for (int q = 0; q < 8; q++) accs4[q] = make_float4(0.f,0.f,0.f,0.f);
    #pragma unroll
    for (int q = 0; q < 3; q++) accv4[q] = make_float4(0.f,0.f,0.f,0.f);
    float den = 0.f;

    #pragma unroll
    for (int r = 0; r < 32; r++){
      const int base = (r*2 + c)*4 + h;
      const float* khp = &KH[base*24];
      float en = 0.f;
      #pragma unroll
      for (int ee = 0; ee < 8; ee++){
        float a0 = qh[ee]      + khp[ee];
        float a1 = qh[8 + ee]  + khp[8 + ee];
        float a2 = qh[16 + ee] + khp[16 + ee];
        en = fmaf(sqrtf(fmaxf(a0*a0 + a1*a1 + a2*a2, 1e-8f)), wsn[ee], en);
      }
      // no max-subtraction: |ev| small (0.177-scaled O(1) logits), f32-safe
      const float w = __expf((eq + EK[base] + en + wb) * 0.17677669529663687f);
      den += w;
      const float4* vp4 = (const float4*)&VS[base*36];
      #pragma unroll
      for (int q = 0; q < 8; q++){
        float4 t4 = vp4[q];
        accs4[q].x = fmaf(w, t4.x, accs4[q].x);
        accs4[q].y = fmaf(w, t4.y, accs4[q].y);
        accs4[q].z = fmaf(w, t4.z, accs4[q].z);
        accs4[q].w = fmaf(w, t4.w, accs4[q].w);
      }
      const float4* vv4 = (const float4*)&VVt[base*12];
      #pragma unroll
      for (int q = 0; q < 3; q++){
        float4 t4 = vv4[q];
        accv4[q].x = fmaf(w, t4.x, accv4[q].x);
        accv4[q].y = fmaf(w, t4.y, accv4[q].y);
        accv4[q].z = fmaf(w, t4.z, accv4[q].z);
        accv4[q].w = fmaf(w, t4.w, accv4[q].w);
      }
    }
    const float inv = 1.f / den;
    float4* po = (float4*)&out[row*128 + h*32];
    #pragma unroll
    for (int q = 0; q < 8; q++){
      float4 t4 = accs4[q];
      t4.x *= inv; t4.y *= inv; t4.z *= inv; t4.w *= inv;
      po[q] = t4;
    }
    float4* pv = (float4*)&out[NC_*128 + row*48 + h*12];
    #pragma unroll
    for (int q = 0; q < 3; q++){
      float4 t4 = accv4[q];
      t4.x *= inv; t4.y *= inv; t4.z *= inv; t4.w *= inv;
      pv[q] = t4;
    }
  }
}

extern "C" void kernel_launch(void* const* d_in, const int* in_sizes, int n_in,
                              void* d_out, int out_size, void* d_ws, size_t ws_size,
                              hipStream_t stream)
{
  fptr s        = (fptr)d_in[0];
  fptr v        = (fptr)d_in[1];
  fptr wp_wh    = (fptr)d_in[2];
  fptr wp_ws_w  = (fptr)d_in[3];
  fptr wp_ws_b  = (fptr)d_in[4];
  fptr q_wh     = (fptr)d_in[5];
  fptr q_ws_w   = (fptr)d_in[6];
  fptr q_ws_b   = (fptr)d_in[7];
  fptr q_wv     = (fptr)d_in[8];
  fptr q_wsv_w  = (fptr)d_in[9];
  fptr q_wsv_b  = (fptr)d_in[10];
  fptr k_wh     = (fptr)d_in[11];
  fptr k_ws_w   = (fptr)d_in[12];
  fptr k_ws_b   = (fptr)d_in[13];
  fptr k_wv     = (fptr)d_in[14];
  fptr k_wsv_w  = (fptr)d_in[15];
  fptr k_wsv_b  = (fptr)d_in[16];
  fptr vv_wh    = (fptr)d_in[17];
  fptr vv_ws_w  = (fptr)d_in[18];
  fptr vv_ws_b  = (fptr)d_in[19];
  fptr vv_wv    = (fptr)d_in[20];
  fptr vv_wsv_w = (fptr)d_in[21];
  fptr vv_wsv_b = (fptr)d_in[22];
  fptr attn_wh  = (fptr)d_in[23];
  fptr attn_ws_w= (fptr)d_in[24];
  fptr attn_ws_b= (fptr)d_in[25];

  float* ws   = (float*)d_ws;
  float* pexp = ws + OFF_LG;
  float* eqh  = ws + OFF_EQH;
  float* sg   = ws + OFF_SG;
  float* tkh  = ws + OFF_TKH;
  float* tek  = ws + OFF_TEK;
  float* tvs  = ws + OFF_TVS;
  float* tvv  = ws + OFF_TVV;

  hipMemsetAsync(sg, 0, 64*SGSTRIDE_*sizeof(float), stream);

  kA<<<NC_/16, 256, 0, stream>>>(s, v, wp_wh, wp_ws_w, wp_ws_b,
                                 q_wh, q_ws_w, q_ws_b, q_wv, q_wsv_w, q_wsv_b,
                                 attn_wh, attn_ws_w, pexp, eqh);
  kAccum<<<800, 256, 0, stream>>>(pexp, s, v, sg);
  kSmall<<<64, 256, 0, stream>>>(sg,
                                 k_wh, k_ws_w, k_ws_b, k_wv, k_wsv_w, k_wsv_b,
                                 vv_wh, vv_ws_w, vv_ws_b, vv_wv, vv_wsv_w, vv_wsv_b,
                                 attn_wh, attn_ws_w, tkh, tek, tvs, tvv);
  kAttn<<<(NC_ + 127)/128, 512, 0, stream>>>(eqh, tkh, tek, tvs, tvv,
                                             attn_ws_w, attn_ws_b, (float*)d_out);
}

// Round 13
// 240.796 us; speedup vs baseline: 2.8411x; 1.0167x over previous
//
#include <hip/hip_runtime.h>
#include <hip/hip_bf16.h>

// GVPDynamicProjection: N=10000, C=2, SI=128, VI=16, H=4, R=32, SH=32, VH=4
// Inputs/outputs: float32. R13 = R12 with the kA v-staging bug fixed:
// R12 wrote `if (tid < 8*48)` (384 > 256 threads) so VVs rows 5-7 were
// uninitialized LDS -> NaN. Restored the strided loop.
// R12 theory unchanged: kA 8 rows/block (2500 blocks, ~17KB LDS, 8 blocks/CU
// vs R11's 5 at 44% occ; R7 measured fewer-rows-wins on the latency-bound
// weight stream). sg zeroing folded into kA block 0 (memset node deleted).
// kAccum / kSmall / kAttn byte-identical to R11.

#define N_  10000
#define C_  2
#define SI_ 128
#define VI_ 16
#define H_  4
#define R_  32
#define SH_ 32
#define VH_ 4
#define NC_ (N_*C_)

typedef const float* __restrict__ fptr;

__device__ __forceinline__ float sigm(float x){ return 1.f/(1.f+__expf(-x)); }

// ---------------- ws layout (float offsets) ----------------
// pexp : [C_*32][N_]   exp(logits), TRANSPOSED      640000
// eqh  : [NC_][100]    per-row eq[4] @0, qh[96] @8  2000000
// sg   : [64][180]     sums: d<176 = sum e^l*x, 176 = sum e^l (zeroed by kA blk0)
// tkh/tek/tvs/tvv: attn tables
#define OFF_LG   0
#define OFF_EQH  640000
#define OFF_SG   2640000
#define OFF_TKH  2651520
#define OFF_TEK  2657664
#define OFF_TVS  2657920
#define OFF_TVV  2666112

#define SGSTRIDE_ 180

// ================= kernel A: per-row logits + q-path =================
// 256 threads, 8 rows/block; grid = NC_/8 = 2500; ~17KB LDS -> 8 blocks/CU
__global__ __launch_bounds__(256) void kA(
    fptr s, fptr v,
    fptr wp_wh, fptr wp_ws_w, fptr wp_ws_b,
    fptr q_wh, fptr q_ws_w, fptr q_ws_b, fptr q_wv, fptr q_wsv_w, fptr q_wsv_b,
    fptr attn_wh, fptr attn_ws_w,
    float* __restrict__ pexp, float* __restrict__ eqh,
    float* __restrict__ sgz)
{
  // ARENA: phase 0-2 = XT transposed [j][row], stride 12 (16B-aligned float4:
  //        j*48B always 16B-aligned, rgA*4 floats = 16B)
  //        j: 0..127 = s, 128..143 = vn_q, 144..159 = vn_p
  //        phase 2c+ = SIG [8][128] (1024 <= 1920), aliases dead XT
  __shared__ __align__(16) float ARENA[160*12];
  __shared__ __align__(16) float VVs[8*48];
  __shared__ __align__(16) float VHQ[8*48];
  __shared__ __align__(16) float SO[8*128];
  __shared__ __align__(16) float GATE[8*16];
  __shared__ __align__(16) float QV[8*48];
  float* const XT  = ARENA;
  float* const SIG = ARENA;

  const int tid  = threadIdx.x;
  const int row0 = blockIdx.x * 8;

  // block 0 also zeroes sg (kAccum is stream-ordered after all kA blocks)
  if (blockIdx.x == 0){
    for (int i = tid; i < 64*SGSTRIDE_; i += 256) sgz[i] = 0.f;
  }

  // phase 0: stage s, v  (STRIDED loops — R12's `if (tid < 384)` bug fixed)
  for (int idx = tid; idx < 8*128; idx += 256){
    int r = idx >> 7, j = idx & 127;
    XT[j*12 + r] = s[(row0+r)*128 + j];
  }
  for (int idx = tid; idx < 8*48; idx += 256){
    int r = idx / 48, k = idx - r*48;
    VVs[r*48 + k] = v[(row0+r)*48 + k];
  }
  __syncthreads();

  // phase 1: vh / vn, 8 rows x 32 (path,i) = 256 threads exactly
  {
    int r = tid >> 5, ii = tid & 31, path = ii >> 4, i = ii & 15;
    fptr wh = path ? wp_wh : q_wh;
    float h0=0.f, h1=0.f, h2=0.f;
    #pragma unroll
    for (int j = 0; j < 16; j++){
      float w = wh[j*16 + i];
      h0 = fmaf(VVs[r*48 + j*3 + 0], w, h0);
      h1 = fmaf(VVs[r*48 + j*3 + 1], w, h1);
      h2 = fmaf(VVs[r*48 + j*3 + 2], w, h2);
    }
    float vn = sqrtf(fmaxf(h0*h0 + h1*h1 + h2*h2, 1e-8f));
    if (!path){
      VHQ[r*48 +  0 + i] = h0;
      VHQ[r*48 + 16 + i] = h1;
      VHQ[r*48 + 32 + i] = h2;
      XT[(128+i)*12 + r] = vn;
    } else {
      XT[(144+i)*12 + r] = vn;
    }
  }
  __syncthreads();

  // phase 2a: so = [s, vn_q] @ q_ws_w + b (8 rows x 128 cols); acc stays live
  const int colA = tid & 127, rgA = tid >> 7;   // rgA in {0,1}, 4 rows each
  float acc[4];
  {
    float bqs = q_ws_b[colA];
    #pragma unroll
    for (int k = 0; k < 4; k++) acc[k] = bqs;
    #pragma unroll 8
    for (int j = 0; j < 144; j++){
      float w = q_ws_w[j*128 + colA];
      float4 x0 = *(const float4*)&XT[j*12 + rgA*4];
      acc[0] = fmaf(x0.x, w, acc[0]); acc[1] = fmaf(x0.y, w, acc[1]);
      acc[2] = fmaf(x0.z, w, acc[2]); acc[3] = fmaf(x0.w, w, acc[3]);
    }
  }
  // phase 2b: logits -> store EXP(logit), TRANSPOSED pexp[(c*32+a)][n]
  {
    const int col = tid & 31, rg = tid >> 5;    // rg in [0,8) = 1 row each
    float a0 = wp_ws_b[col];
    #pragma unroll 8
    for (int j = 0; j < 144; j++){
      int jj = (j < 128) ? j : (j + 16);
      a0 = fmaf(XT[jj*12 + rg], wp_ws_w[j*32 + col], a0);
    }
    const int c = rg & 1, n = (row0 + rg) >> 1; // row0 even
    pexp[(c*32 + col)*N_ + n] = __expf(a0);     // no max-sub: |l|<~8, f32-safe
  }
  __syncthreads();                              // XT dead; SIG live

  // phase 2c: sig/silu once from registers
  #pragma unroll
  for (int k = 0; k < 4; k++){
    float so = acc[k];
    float sg_ = sigm(so);
    SIG[(rgA*4 + k)*128 + colA] = sg_;
    SO [(rgA*4 + k)*128 + colA] = so * sg_;     // silu
  }
  __syncthreads();

  // phase 3: gate = sigmoid(sig_so @ q_wsv_w + b)  (8 rows x 16 = 128 thr)
  if (tid < 128){
    const int r = tid >> 4, g = tid & 15;
    float ga = q_wsv_b[g];
    #pragma unroll 8
    for (int o = 0; o < 128; o += 4){
      float4 s4 = *(const float4*)&SIG[r*128 + o];
      ga = fmaf(s4.x, q_wsv_w[(o+0)*16 + g], ga);
      ga = fmaf(s4.y, q_wsv_w[(o+1)*16 + g], ga);
      ga = fmaf(s4.z, q_wsv_w[(o+2)*16 + g], ga);
      ga = fmaf(s4.w, q_wsv_w[(o+3)*16 + g], ga);
    }
    GATE[r*16 + g] = sigm(ga);
  } else if (tid < 160){
    // phase 4: eq[h] = silu_so_head . ws_q  (8 rows x 4 h = 32 thr)
    const int t2 = tid - 128, r = t2 >> 2, h = t2 & 3;
    float e = 0.f;
    #pragma unroll
    for (int t = 0; t < 32; t++)
      e = fmaf(SO[r*128 + h*32 + t], attn_ws_w[t], e);
    eqh[(row0 + r)*100 + h] = e;
  }
  __syncthreads();

  // phase 5: qv = (vh_q @ q_wv)^T * gate   (8*48 = 384 work items)
  for (int t = tid; t < 8*48; t += 256){
    int r = t / 48, k = t - r*48, i = k / 3, d = k - i*3;
    float a = 0.f;
    #pragma unroll
    for (int j = 0; j < 16; j++)
      a = fmaf(VHQ[r*48 + d*16 + j], q_wv[j*16 + i], a);
    QV[r*48 + k] = a * GATE[r*16 + i];
  }
  __syncthreads();

  // phase 6: qh[h][d][e] = sum_i qv[h*4+i][d] * wh_q[i][e]  (8*96 = 768)
  for (int t = tid; t < 8*96; t += 256){
    int r = t / 96, k = t - r*96;
    int h = k / 24, rem = k - h*24, d = rem >> 3, ee = rem & 7;
    float a = 0.f;
    #pragma unroll
    for (int i = 0; i < 4; i++)
      a = fmaf(QV[r*48 + (h*4 + i)*3 + d], attn_wh[i*8 + ee], a);
    eqh[(row0 + r)*100 + 8 + k] = a;
  }
}

// ===== kAccum: weighted sums via atomics, 800 blocks = 3200 waves ==========
__global__ __launch_bounds__(256) void kAccum(const float* __restrict__ pexp,
                                              fptr s, fptr v,
                                              float* __restrict__ sg)
{
  const int b = blockIdx.x;
  const int c = b & 1, ah = (b >> 1) & 1, chunk = b >> 2;
  const int n0 = chunk * 50;
  const int tid = threadIdx.x;
  const int ag = tid >> 6, dl = tid & 63;
  const int abase = ah*16 + ag*4;

  const float* pb = pexp + (c*32 + abase)*N_;
  float acc[4][3] = {};
  float dn[4] = {};

  #pragma unroll 2
  for (int n = n0; n < n0 + 50; n++){
    const int rc = n*2 + c;
    float pw[4];
    #pragma unroll
    for (int aa = 0; aa < 4; aa++){
      pw[aa] = pb[aa*N_ + n];
      dn[aa] += pw[aa];
    }
    #pragma unroll
    for (int dd = 0; dd < 3; dd++){
      int d = dl + 64*dd;
      if (d < 176){
        float xv = (d < 128) ? s[rc*128 + d] : v[rc*48 + d - 128];
        #pragma unroll
        for (int aa = 0; aa < 4; aa++)
          acc[aa][dd] = fmaf(pw[aa], xv, acc[aa][dd]);
      }
    }
  }
  #pragma unroll
  for (int aa = 0; aa < 4; aa++){
    const int base = (c*32 + abase + aa)*SGSTRIDE_;
    #pragma unroll
    for (int dd = 0; dd < 3; dd++){
      int d = dl + 64*dd;
      if (d < 176) atomicAdd(&sg[base + d], acc[aa][dd]);
    }
    if (dl == 0) atomicAdd(&sg[base + 176], dn[aa]);
  }
}

// ================= kSmall: normalize + k/vv GVP + attn tables ===============
__global__ __launch_bounds__(256) void kSmall(
    const float* __restrict__ sg,
    fptr k_wh, fptr k_ws_w, fptr k_ws_b, fptr k_wv, fptr k_wsv_w, fptr k_wsv_b,
    fptr vv_wh, fptr vv_ws_w, fptr vv_ws_b, fptr vv_wv, fptr vv_wsv_w, fptr vv_wsv_b,
    fptr attn_wh, fptr attn_ws_w,
    float* __restrict__ tkh, float* __restrict__ tek,
    float* __restrict__ tvs, float* __restrict__ tvv)
{
  const int b = blockIdx.x, r = b >> 1, c = b & 1;
  const int tid = threadIdx.x;
  __shared__ float X[176];
  __shared__ float VN[2][16];
  __shared__ float VH[2][48];
  __shared__ float SOk[128], SOv[128];
  __shared__ float G[2][16];
  __shared__ float KV[48];

  if (tid < 176){
    const float* p = sg + (c*32 + r)*SGSTRIDE_;
    X[tid] = p[tid] / p[176];
  }
  __syncthreads();

  if (tid < 32){
    int path = tid >> 4, i = tid & 15;
    fptr wh = path ? vv_wh : k_wh;
    float h0=0.f, h1=0.f, h2=0.f;
    #pragma unroll
    for (int j = 0; j < 16; j++){
      float w = wh[j*16 + i];
      h0 = fmaf(X[128 + j*3 + 0], w, h0);
      h1 = fmaf(X[128 + j*3 + 1], w, h1);
      h2 = fmaf(X[128 + j*3 + 2], w, h2);
    }
    VH[path][ 0 + i] = h0; VH[path][16 + i] = h1; VH[path][32 + i] = h2;
    VN[path][i] = sqrtf(fmaxf(h0*h0 + h1*h1 + h2*h2, 1e-8f));
  }
  __syncthreads();

  {
    int path = tid >> 7, col = tid & 127;
    fptr W  = path ? vv_ws_w : k_ws_w;
    fptr Bb = path ? vv_ws_b : k_ws_b;
    float so = Bb[col];
    for (int j = 0; j < 128; j++) so = fmaf(X[j], W[j*128 + col], so);
    #pragma unroll
    for (int i = 0; i < 16; i++)  so = fmaf(VN[path][i], W[(128+i)*128 + col], so);
    (path ? SOv : SOk)[col] = so;
  }
  __syncthreads();

  if (tid < 32){
    int path = tid >> 4, g = tid & 15;
    fptr Wsv = path ? vv_wsv_w : k_wsv_w;
    fptr Bsv = path ? vv_wsv_b : k_wsv_b;
    const float* SOp = path ? SOv : SOk;
    float ga = Bsv[g];
    for (int o = 0; o < 128; o++)
      ga = fmaf(sigm(SOp[o]), Wsv[o*16 + g], ga);
    G[path][g] = sigm(ga);
  } else if (tid < 36){
    int h = tid - 32;
    float e = 0.f;
    #pragma unroll
    for (int t = 0; t < 32; t++){
      float so = SOk[h*32 + t];
      e = fmaf(so * sigm(so), attn_ws_w[32 + t], e);
    }
    tek[(r*2 + c)*4 + h] = e;
  } else if (tid >= 64 && tid < 192){
    int o = tid - 64;
    float so = SOv[o];
    tvs[(r*2 + c)*128 + o] = so * sigm(so);
  }
  __syncthreads();

  if (tid < 96){
    int path = tid / 48, k = tid % 48, i = k / 3, d = k - i*3;
    fptr Wv = path ? vv_wv : k_wv;
    float vo = 0.f;
    #pragma unroll
    for (int j = 0; j < 16; j++)
      vo = fmaf(VH[path][d*16 + j], Wv[j*16 + i], vo);
    float gv = vo * G[path][i];
    if (path == 0) KV[k] = gv;
    else {
      int h = i >> 2, ii = i & 3;
      tvv[(((r*2 + c)*4 + h)*4 + ii)*3 + d] = gv;
    }
  }
  __syncthreads();

  if (tid < 96){
    int h = tid / 24, rem = tid % 24, d = rem >> 3, ee = rem & 7;
    float a = 0.f;
    #pragma unroll
    for (int i = 0; i < 4; i++)
      a = fmaf(KV[(h*4 + i)*3 + d], attn_wh[(4 + i)*8 + ee], a);
    tkh[((r*2 + c)*4 + h)*24 + d*8 + ee] = a;
  }
}

// ================= kAttn (R9-measured): one row/thread ======================
__global__ __launch_bounds__(512, 1) void kAttn(
    const float* __restrict__ eqh,
    const float* __restrict__ tkh, const float* __restrict__ tek,
    const float* __restrict__ tvs, const float* __restrict__ tvv,
    fptr attn_ws_w, fptr attn_ws_b,
    float* __restrict__ out)
{
  __shared__ __align__(16) float KH[6144];
  __shared__ __align__(16) float EK[256];
  __shared__ __align__(16) float VS[256*36];
  __shared__ __align__(16) float VVt[3072];
  const int tid = threadIdx.x;

  for (int i = tid; i < 6144; i += 512) KH[i] = tkh[i];
  if (tid < 256) EK[tid] = tek[tid];
  for (int i = tid; i < 8192; i += 512){ int base = i >> 5, t = i & 31; VS[base*36 + t] = tvs[i]; }
  for (int i = tid; i < 3072; i += 512) VVt[i] = tvv[i];

  float wsn[8];
  #pragma unroll
  for (int ee = 0; ee < 8; ee++) wsn[ee] = attn_ws_w[64 + ee];
  const float wb = attn_ws_b[0];
  __syncthreads();

  const int row = blockIdx.x*128 + (tid >> 2);
  const int h = tid & 3;
  if (row < NC_){
    const int c = row & 1;
    const float eq = eqh[row*100 + h];
    float qh[24];
    {
      const float4* qp = (const float4*)&eqh[row*100 + 8 + h*24];
      #pragma unroll
      for (int k = 0; k < 6; k++){
        float4 t4 = qp[k];
        qh[k*4+0] = t4.x; qh[k*4+1] = t4.y; qh[k*4+2] = t4.z; qh[k*4+3] = t4.w;
      }
    }
    float4 accs4[8];
    float4 accv4[3];
    #pragma unroll
    for (int q = 0; q < 8; q++) accs4[q] = make_float4(0.f,0.f,0.f,0.f);
    #pragma unroll
    for (int q = 0; q < 3; q++) accv4[q] = make_float4(0.f,0.f,0.f,0.f);
    float den = 0.f;

    #pragma unroll
    for (int r = 0; r < 32; r++){
      const int base = (r*2 + c)*4 + h;
      const float* khp = &KH[base*24];
      float en = 0.f;
      #pragma unroll
      for (int ee = 0; ee < 8; ee++){
        float a0 = qh[ee]      + khp[ee];
        float a1 = qh[8 + ee]  + khp[8 + ee];
        float a2 = qh[16 + ee] + khp[16 + ee];
        en = fmaf(sqrtf(fmaxf(a0*a0 + a1*a1 + a2*a2, 1e-8f)), wsn[ee], en);
      }
      const float w = __expf((eq + EK[base] + en + wb) * 0.17677669529663687f);
      den += w;
      const float4* vp4 = (const float4*)&VS[base*36];
      #pragma unroll
      for (int q = 0; q < 8; q++){
        float4 t4 = vp4[q];
        accs4[q].x = fmaf(w, t4.x, accs4[q].x);
        accs4[q].y = fmaf(w, t4.y, accs4[q].y);
        accs4[q].z = fmaf(w, t4.z, accs4[q].z);
        accs4[q].w = fmaf(w, t4.w, accs4[q].w);
      }
      const float4* vv4 = (const float4*)&VVt[base*12];
      #pragma unroll
      for (int q = 0; q < 3; q++){
        float4 t4 = vv4[q];
        accv4[q].x = fmaf(w, t4.x, accv4[q].x);
        accv4[q].y = fmaf(w, t4.y, accv4[q].y);
        accv4[q].z = fmaf(w, t4.z, accv4[q].z);
        accv4[q].w = fmaf(w, t4.w, accv4[q].w);
      }
    }
    const float inv = 1.f / den;
    float4* po = (float4*)&out[row*128 + h*32];
    #pragma unroll
    for (int q = 0; q < 8; q++){
      float4 t4 = accs4[q];
      t4.x *= inv; t4.y *= inv; t4.z *= inv; t4.w *= inv;
      po[q] = t4;
    }
    float4* pv = (float4*)&out[NC_*128 + row*48 + h*12];
    #pragma unroll
    for (int q = 0; q < 3; q++){
      float4 t4 = accv4[q];
      t4.x *= inv; t4.y *= inv; t4.z *= inv; t4.w *= inv;
      pv[q] = t4;
    }
  }
}

extern "C" void kernel_launch(void* const* d_in, const int* in_sizes, int n_in,
                              void* d_out, int out_size, void* d_ws, size_t ws_size,
                              hipStream_t stream)
{
  fptr s        = (fptr)d_in[0];
  fptr v        = (fptr)d_in[1];
  fptr wp_wh    = (fptr)d_in[2];
  fptr wp_ws_w  = (fptr)d_in[3];
  fptr wp_ws_b  = (fptr)d_in[4];
  fptr q_wh     = (fptr)d_in[5];
  fptr q_ws_w   = (fptr)d_in[6];
  fptr q_ws_b   = (fptr)d_in[7];
  fptr q_wv     = (fptr)d_in[8];
  fptr q_wsv_w  = (fptr)d_in[9];
  fptr q_wsv_b  = (fptr)d_in[10];
  fptr k_wh     = (fptr)d_in[11];
  fptr k_ws_w   = (fptr)d_in[12];
  fptr k_ws_b   = (fptr)d_in[13];
  fptr k_wv     = (fptr)d_in[14];
  fptr k_wsv_w  = (fptr)d_in[15];
  fptr k_wsv_b  = (fptr)d_in[16];
  fptr vv_wh    = (fptr)d_in[17];
  fptr vv_ws_w  = (fptr)d_in[18];
  fptr vv_ws_b  = (fptr)d_in[19];
  fptr vv_wv    = (fptr)d_in[20];
  fptr vv_wsv_w = (fptr)d_in[21];
  fptr vv_wsv_b = (fptr)d_in[22];
  fptr attn_wh  = (fptr)d_in[23];
  fptr attn_ws_w= (fptr)d_in[24];
  fptr attn_ws_b= (fptr)d_in[25];

  float* ws   = (float*)d_ws;
  float* pexp = ws + OFF_LG;
  float* eqh  = ws + OFF_EQH;
  float* sg   = ws + OFF_SG;
  float* tkh  = ws + OFF_TKH;
  float* tek  = ws + OFF_TEK;
  float* tvs  = ws + OFF_TVS;
  float* tvv  = ws + OFF_TVV;

  kA<<<NC_/8, 256, 0, stream>>>(s, v, wp_wh, wp_ws_w, wp_ws_b,
                                q_wh, q_ws_w, q_ws_b, q_wv, q_wsv_w, q_wsv_b,
                                attn_wh, attn_ws_w, pexp, eqh, sg);
  kAccum<<<800, 256, 0, stream>>>(pexp, s, v, sg);
  kSmall<<<64, 256, 0, stream>>>(sg,
                                 k_wh, k_ws_w, k_ws_b, k_wv, k_wsv_w, k_wsv_b,
                                 vv_wh, vv_ws_w, vv_ws_b, vv_wv, vv_wsv_w, vv_wsv_b,
                                 attn_wh, attn_ws_w, tkh, tek, tvs, tvv);
  kAttn<<<(NC_ + 127)/128, 512, 0, stream>>>(eqh, tkh, tek, tvs, tvv,
                                             attn_ws_w, attn_ws_b, (float*)d_out);
}